// Round 14
// baseline (420.488 us; speedup 1.0000x reference)
//
#include <hip/hip_runtime.h>

#define T_LEN 16384
#define NSEC 6                   // order-5 butter = 3 SOS each (hp+lp)
#define NSTATE 12
#define NMAT (NSTATE * NSTATE)   // 144
#define L_SMP 64                 // samples per thread
#define NPOW 5                   // M^(2^i), i=0..4, M = A^64 (window 32)
#define NTAB (NPOW + 1)          // + slot 5 = A^32
#define NTHR 256                 // 1 signal per block; 4 waves
#define NS_TOT 2048

// g_Mp[0..4] = (A^64)^(2^i); g_Mp[5] = A^32. fp32, built in fp64.
__device__ float g_Mp[NTAB * NMAT];
// Phi(t) = C * A^t, t=0..31 (row vectors), fp32.
__device__ float g_Phi[32 * NSTATE];

__device__ __forceinline__ float rfl(float v) {
    return __int_as_float(__builtin_amdgcn_readfirstlane(__float_as_int(v)));
}

// ---------------------------------------------------------------------------
// Build one-step transition A (fp64); Phi(t)=C*A^t, t=0..31; square 10x,
// storing A^32 (it=5) and (A^64)^(2^i) (it=6..10).
// ---------------------------------------------------------------------------
__global__ void k_matpow(const float* __restrict__ sos) {
    __shared__ double A[NMAT];
    __shared__ double ph[2][NSTATE];
    int tid = threadIdx.x;

    if (tid < NSTATE) {
        double b0[NSEC], b1[NSEC], b2[NSEC], a1[NSEC], a2[NSEC];
#pragma unroll
        for (int i = 0; i < NSEC; ++i) {
            b0[i] = (double)sos[i * 6 + 0];
            b1[i] = (double)sos[i * 6 + 1];
            b2[i] = (double)sos[i * 6 + 2];
            a1[i] = (double)sos[i * 6 + 4];
            a2[i] = (double)sos[i * 6 + 5];
        }
        double w1[NSEC], w2[NSEC];
#pragma unroll
        for (int i = 0; i < NSEC; ++i) {
            w1[i] = (tid == 2 * i) ? 1.0 : 0.0;
            w2[i] = (tid == 2 * i + 1) ? 1.0 : 0.0;
        }
        double cur = 0.0;   // zero input: unit-state probe, one step
#pragma unroll
        for (int i = 0; i < NSEC; ++i) {
            double yv = fma(b0[i], cur, w1[i]);
            double n1 = fma(b1[i], cur, fma(-a1[i], yv, w2[i]));
            double n2 = fma(b2[i], cur, -(a2[i] * yv));
            w1[i] = n1; w2[i] = n2; cur = yv;
        }
#pragma unroll
        for (int i = 0; i < NSEC; ++i) {
            A[(2 * i) * NSTATE + tid]     = w1[i];   // column tid
            A[(2 * i + 1) * NSTATE + tid] = w2[i];
        }
        // C row: y(zero input) = sum_i w1_i * prod_{j>i} b0_j
        double c = 0.0;
        if ((tid & 1) == 0) {
            int i = tid >> 1;
            double p = 1.0;
            for (int j = i + 1; j < NSEC; ++j) p *= (double)sos[j * 6 + 0];
            c = p;
        }
        ph[0][tid] = c;
    }
    __syncthreads();

    // Phi(t) = C * A^t (row-vector iteration, double-buffered)
    for (int t = 0; t < 32; ++t) {
        if (tid < NSTATE) {
            g_Phi[t * NSTATE + tid] = (float)ph[t & 1][tid];
            double v = 0.0;
#pragma unroll
            for (int kk = 0; kk < NSTATE; ++kk)
                v = fma(ph[t & 1][kk], A[kk * NSTATE + tid], v);
            ph[(t + 1) & 1][tid] = v;
        }
        __syncthreads();
    }

    const int rr = tid / NSTATE, cc = tid % NSTATE;
    for (int it = 1; it <= 10; ++it) {
        double v = 0.0;
        if (tid < NMAT) {
#pragma unroll
            for (int kk = 0; kk < NSTATE; ++kk)
                v = fma(A[rr * NSTATE + kk], A[kk * NSTATE + cc], v);
        }
        __syncthreads();
        if (tid < NMAT) {
            A[rr * NSTATE + cc] = v;
            if (it == 5) g_Mp[5 * NMAT + tid] = (float)v;          // A^32
            if (it >= 6) g_Mp[(it - 6) * NMAT + tid] = (float)v;   // (A^64)^(2^i)
        }
        __syncthreads();
    }
}

// In-place block-triangular matvec: V <- M*V + EXTRA. M block-lower-triangular
// (biquad cascade): rows 2p,2p+1 read V[0..2p+1] only -> pair-descending
// in-place safe. Rows read as float4 from LDS (broadcast). EXTRA0/EXTRA1 are
// expressions in p.
#define TRI_MATVEC_IP(MBASE, V, EXTRA0, EXTRA1)                                 \
    {                                                                           \
        _Pragma("unroll")                                                       \
        for (int p = 5; p >= 0; --p) {                                          \
            float o0, o1;                                                       \
            _Pragma("unroll")                                                   \
            for (int rq = 0; rq < 2; ++rq) {                                    \
                const int q = 2 * p + rq;                                       \
                const float4* row = (const float4*)((MBASE) + q * NSTATE);      \
                float acc = (rq == 0 ? (EXTRA0) : (EXTRA1));                    \
                float4 r0 = row[0];                                             \
                acc = fmaf(r0.x, (V)[0], acc);                                  \
                acc = fmaf(r0.y, (V)[1], acc);                                  \
                if (p >= 1) { acc = fmaf(r0.z, (V)[2], acc);                    \
                              acc = fmaf(r0.w, (V)[3], acc); }                  \
                if (p >= 2) {                                                   \
                    float4 r1 = row[1];                                         \
                    acc = fmaf(r1.x, (V)[4], acc);                              \
                    acc = fmaf(r1.y, (V)[5], acc);                              \
                    if (p >= 3) { acc = fmaf(r1.z, (V)[6], acc);                \
                                  acc = fmaf(r1.w, (V)[7], acc); }              \
                }                                                               \
                if (p >= 4) {                                                   \
                    float4 r2 = row[2];                                         \
                    acc = fmaf(r2.x, (V)[8], acc);                              \
                    acc = fmaf(r2.y, (V)[9], acc);                              \
                    if (p >= 5) { acc = fmaf(r2.z, (V)[10], acc);               \
                                  acc = fmaf(r2.w, (V)[11], acc); }             \
                }                                                               \
                if (rq == 0) o0 = acc; else o1 = acc;                           \
            }                                                                   \
            (V)[2 * p] = o0; (V)[2 * p + 1] = o1;                               \
        }                                                                       \
    }

// ---------------------------------------------------------------------------
// One 256-thread block per signal. Thread t owns samples [t*64, t*64+64).
//   passA: TWO independent 32-sample zero-state chains (2x ILP):
//          chain A: samples 0..31 -> y_zs + s_half; chain B: 32..63 -> y'_zs + s'B
//   stitch: c0 = A^32*s_half + s'B   (linearity; exact)
//   scan  : 5-round wave-local shuffle scan (M=A^64, window 32 decay-safe)
//   seed  : si = excl scan + M^lane * T_prevwave (lanes<32)
//   s32   : A^32*si + s_half  (s_half parked in LDS across the scan)
//   passB : t<32: y = y_zs + Phi(t)*si ; t>=32: y = y'_zs + Phi(t-32)*s32
//   write : 2 rounds x 32KB swizzled LDS staging (direct stores amplify 2x, R13)
// ---------------------------------------------------------------------------
__global__ void __launch_bounds__(NTHR, 4)
k_main(const float* __restrict__ x, const float* __restrict__ sos,
       float* __restrict__ y) {
    __shared__ float Mp[NTAB][NMAT];     // 3.46 KB ([5] = A^32)
    __shared__ float Ph[32 * NSTATE];    // 1.5 KB
    __shared__ float cw[4][NSTATE];      // per-wave totals
    __shared__ float4 sm4[2048];         // 32 KB write-stage; aliased: s_half park
    float* shalf = (float*)sm4;          // [256][13] (13.3 KB, stride-13: no bank hot-spot)

    const int k = threadIdx.x;
    const int lane = k & 63;
    const int w = k >> 6;                // wave id 0..3
    const int sig = blockIdx.x;

    // front-load stash (HBM latency hides under table staging)
    const float4* xp4 = (const float4*)(x + (size_t)sig * T_LEN) + k * 16;
    float4 stash[16];
#pragma unroll
    for (int m = 0; m < 16; ++m) stash[m] = xp4[m];

    // stage tables
    for (int i = k; i < NTAB * NMAT; i += NTHR)
        Mp[i / NMAT][i % NMAT] = g_Mp[i];
    for (int i = k; i < 32 * NSTATE; i += NTHR)
        Ph[i] = g_Phi[i];

    // coefficients -> SGPRs
    float b0[NSEC], b1[NSEC], b2[NSEC], a1[NSEC], a2[NSEC];
#pragma unroll
    for (int i = 0; i < NSEC; ++i) {
        b0[i] = rfl(sos[i * 6 + 0]);
        b1[i] = rfl(sos[i * 6 + 1]);
        b2[i] = rfl(sos[i * 6 + 2]);
        a1[i] = rfl(sos[i * 6 + 4]);
        a2[i] = rfl(sos[i * 6 + 5]);
    }

    // ---- pass A: two interleaved independent 32-sample chains ----
    float w1a[NSEC], w2a[NSEC], w1b[NSEC], w2b[NSEC];
#pragma unroll
    for (int i = 0; i < NSEC; ++i) { w1a[i] = w2a[i] = w1b[i] = w2b[i] = 0.f; }

    auto fstepA = [&](float cur) -> float {
#pragma unroll
        for (int i = 0; i < NSEC; ++i) {
            float yv = fmaf(b0[i], cur, w1a[i]);
            w1a[i] = fmaf(b1[i], cur, fmaf(-a1[i], yv, w2a[i]));
            w2a[i] = fmaf(b2[i], cur, -(a2[i] * yv));
            cur = yv;
        }
        return cur;
    };
    auto fstepB = [&](float cur) -> float {
#pragma unroll
        for (int i = 0; i < NSEC; ++i) {
            float yv = fmaf(b0[i], cur, w1b[i]);
            w1b[i] = fmaf(b1[i], cur, fmaf(-a1[i], yv, w2b[i]));
            w2b[i] = fmaf(b2[i], cur, -(a2[i] * yv));
            cur = yv;
        }
        return cur;
    };

#pragma unroll
    for (int m = 0; m < 8; ++m) {
        float4 va = stash[m], vb = stash[m + 8];
        va.x = fstepA(va.x); vb.x = fstepB(vb.x);
        va.y = fstepA(va.y); vb.y = fstepB(vb.y);
        va.z = fstepA(va.z); vb.z = fstepB(vb.z);
        va.w = fstepA(va.w); vb.w = fstepB(vb.w);
        stash[m] = va; stash[m + 8] = vb;
    }

    // park s_half in LDS (needed after the scan for s32)
#pragma unroll
    for (int i = 0; i < NSEC; ++i) {
        shalf[k * 13 + 2 * i]     = w1a[i];
        shalf[k * 13 + 2 * i + 1] = w2a[i];
    }

    __syncthreads();   // tables staged + shalf written

    // ---- stitch: c0 = A^32 * s_half + s'B ----
    float c0[NSTATE];
#pragma unroll
    for (int i = 0; i < NSEC; ++i) { c0[2 * i] = w1a[i]; c0[2 * i + 1] = w2a[i]; }
    TRI_MATVEC_IP(Mp[5], c0, w1b[p], w2b[p]);

    // ---- wave-local inclusive scan: 5 shuffle rounds (window 32) ----
#pragma unroll
    for (int rnd = 0; rnd < NPOW; ++rnd) {
        const int d = 1 << rnd;
        float pr[NSTATE];
#pragma unroll
        for (int j = 0; j < NSTATE; ++j) pr[j] = __shfl_up(c0[j], d, 64);
        if (lane >= d) {
            TRI_MATVEC_IP(Mp[rnd], pr, c0[2 * p], c0[2 * p + 1]);
#pragma unroll
            for (int j = 0; j < NSTATE; ++j) c0[j] = pr[j];
        }
    }

    if (lane == 63) {
#pragma unroll
        for (int j = 0; j < NSTATE; ++j) cw[w][j] = c0[j];
    }
    __syncthreads();

    // ---- seed: si = exclusive scan; waves>0 lanes<32 add M^lane * T_prev ----
    float si[NSTATE];
#pragma unroll
    for (int j = 0; j < NSTATE; ++j) {
        si[j] = __shfl_up(c0[j], 1, 64);
        if (lane == 0) si[j] = 0.f;
    }
    if (w > 0 && lane < 32) {
        float u[NSTATE];
#pragma unroll
        for (int j = 0; j < NSTATE; ++j) u[j] = cw[w - 1][j];
#pragma unroll
        for (int i = 0; i < NPOW; ++i) {
            if ((lane >> i) & 1) {
                TRI_MATVEC_IP(Mp[i], u, 0.f, 0.f);
            }
        }
#pragma unroll
        for (int j = 0; j < NSTATE; ++j) si[j] += u[j];
    }

    // ---- s32 = A^32 * si + s_half (from LDS) ----
    float s32[NSTATE];
#pragma unroll
    for (int j = 0; j < NSTATE; ++j) s32[j] = si[j];
    TRI_MATVEC_IP(Mp[5], s32, shalf[k * 13 + 2 * p], shalf[k * 13 + 2 * p + 1]);

    // ---- pass B: corrections (ILP-friendly, Phi rows via LDS broadcast) ----
#pragma unroll
    for (int m = 0; m < 16; ++m) {
        const float* st = (m < 8) ? si : s32;
        const int tbase = (m < 8) ? m * 4 : (m - 8) * 4;
        float4 v = stash[m];
        float corr[4];
#pragma unroll
        for (int q = 0; q < 4; ++q) {
            const float4* ph = (const float4*)&Ph[(tbase + q) * NSTATE];
            float4 p0 = ph[0], p1 = ph[1], p2 = ph[2];
            float acc = p0.x * st[0];
            acc = fmaf(p0.y, st[1], acc);
            acc = fmaf(p0.z, st[2], acc);
            acc = fmaf(p0.w, st[3], acc);
            acc = fmaf(p1.x, st[4], acc);
            acc = fmaf(p1.y, st[5], acc);
            acc = fmaf(p1.z, st[6], acc);
            acc = fmaf(p1.w, st[7], acc);
            acc = fmaf(p2.x, st[8], acc);
            acc = fmaf(p2.y, st[9], acc);
            acc = fmaf(p2.z, st[10], acc);
            acc = fmaf(p2.w, st[11], acc);
            corr[q] = acc;
        }
        v.x += corr[0]; v.y += corr[1]; v.z += corr[2]; v.w += corr[3];
        stash[m] = v;
    }

    // ---- write staging: 2 rounds x 32KB, swizzled, coalesced (R13: direct
    //      stores amplify writes 2x -> staging is load-bearing) ----
    float4* yp4 = (float4*)(y + (size_t)sig * T_LEN);
#pragma unroll 1
    for (int r = 0; r < 2; ++r) {
        __syncthreads();                 // shalf reads done (r=0) / prev round (r=1)
        if ((w >> 1) == r) {
            const int base = (w & 1) * 1024;
#pragma unroll
            for (int m = 0; m < 16; ++m)
                sm4[base + lane * 16 + (m ^ (lane & 15))] = stash[m];
        }
        __syncthreads();
#pragma unroll
        for (int q = 0; q < 8; ++q) {
            int j = k + 256 * q;                       // 0..2047
            int s = (j & ~15) | ((j ^ (j >> 4)) & 15); // matches writer swizzle
            yp4[r * 2048 + j] = sm4[s];
        }
    }
}

extern "C" void kernel_launch(void* const* d_in, const int* in_sizes, int n_in,
                              void* d_out, int out_size, void* d_ws, size_t ws_size,
                              hipStream_t stream) {
    const float* x   = (const float*)d_in[0];
    const float* sos = (const float*)d_in[1];
    if (n_in >= 2 && in_sizes[0] <= 256 && in_sizes[1] > 256) {  // insurance
        x = (const float*)d_in[1];
        sos = (const float*)d_in[0];
    }
    float* out = (float*)d_out;

    int NS = out_size / T_LEN;      // 2048 signals
    if (NS > NS_TOT) NS = NS_TOT;
    if (NS < 1) NS = 1;

    k_matpow<<<1, 256, 0, stream>>>(sos);
    k_main<<<NS, NTHR, 0, stream>>>(x, sos, out);
}

// Round 15
// 124.613 us; speedup vs baseline: 3.3744x; 3.3744x over previous
//
#include <hip/hip_runtime.h>

#define T_LEN 16384
#define NSEC 6                   // order-5 butter = 3 SOS each (hp+lp)
#define NSTATE 12
#define NMAT (NSTATE * NSTATE)   // 144
#define NPOW 5                   // M^(2^i), i=0..4, M = A^64 (window 32)
#define NTAB (NPOW + 1)          // + slot 5 = A^32
#define NS_TOT 2048

// g_Mp[0..4] = (A^64)^(2^i); g_Mp[5] = A^32. fp32, built in fp64.
__device__ float g_Mp[NTAB * NMAT];
// Per-32-sample-chunk seed states: [sig][512][NSTATE]  (~50 MB)
__device__ float g_seed[(size_t)NS_TOT * 512 * NSTATE];

__device__ __forceinline__ float rfl(float v) {
    return __int_as_float(__builtin_amdgcn_readfirstlane(__float_as_int(v)));
}

// ---------------------------------------------------------------------------
// Build one-step transition A (fp64); square 10x, storing A^32 (it=5) and
// (A^64)^(2^i) (it=6..10).
// ---------------------------------------------------------------------------
__global__ void k_matpow(const float* __restrict__ sos) {
    __shared__ double A[NMAT];
    int tid = threadIdx.x;

    if (tid < NSTATE) {
        double b0[NSEC], b1[NSEC], b2[NSEC], a1[NSEC], a2[NSEC];
#pragma unroll
        for (int i = 0; i < NSEC; ++i) {
            b0[i] = (double)sos[i * 6 + 0];
            b1[i] = (double)sos[i * 6 + 1];
            b2[i] = (double)sos[i * 6 + 2];
            a1[i] = (double)sos[i * 6 + 4];
            a2[i] = (double)sos[i * 6 + 5];
        }
        double w1[NSEC], w2[NSEC];
#pragma unroll
        for (int i = 0; i < NSEC; ++i) {
            w1[i] = (tid == 2 * i) ? 1.0 : 0.0;
            w2[i] = (tid == 2 * i + 1) ? 1.0 : 0.0;
        }
        double cur = 0.0;   // zero input: unit-state probe, one step
#pragma unroll
        for (int i = 0; i < NSEC; ++i) {
            double yv = fma(b0[i], cur, w1[i]);
            double n1 = fma(b1[i], cur, fma(-a1[i], yv, w2[i]));
            double n2 = fma(b2[i], cur, -(a2[i] * yv));
            w1[i] = n1; w2[i] = n2; cur = yv;
        }
#pragma unroll
        for (int i = 0; i < NSEC; ++i) {
            A[(2 * i) * NSTATE + tid]     = w1[i];   // column tid
            A[(2 * i + 1) * NSTATE + tid] = w2[i];
        }
    }
    __syncthreads();

    const int rr = tid / NSTATE, cc = tid % NSTATE;
    for (int it = 1; it <= 10; ++it) {
        double v = 0.0;
        if (tid < NMAT) {
#pragma unroll
            for (int kk = 0; kk < NSTATE; ++kk)
                v = fma(A[rr * NSTATE + kk], A[kk * NSTATE + cc], v);
        }
        __syncthreads();
        if (tid < NMAT) {
            A[rr * NSTATE + cc] = v;
            if (it == 5) g_Mp[5 * NMAT + tid] = (float)v;          // A^32
            if (it >= 6) g_Mp[(it - 6) * NMAT + tid] = (float)v;   // (A^64)^(2^i)
        }
        __syncthreads();
    }
}

// In-place block-triangular matvec: V <- M*V + EXTRA (expressions in p).
// M block-lower-triangular (biquad cascade): rows 2p,2p+1 read V[0..2p+1]
// only -> pair-descending in-place safe. Rows read as float4 (LDS broadcast).
#define TRI_MATVEC_IP(MBASE, V, EXTRA0, EXTRA1)                                 \
    {                                                                           \
        _Pragma("unroll")                                                       \
        for (int p = 5; p >= 0; --p) {                                          \
            float o0, o1;                                                       \
            _Pragma("unroll")                                                   \
            for (int rq = 0; rq < 2; ++rq) {                                    \
                const int q = 2 * p + rq;                                       \
                const float4* row = (const float4*)((MBASE) + q * NSTATE);      \
                float acc = (rq == 0 ? (EXTRA0) : (EXTRA1));                    \
                float4 r0 = row[0];                                             \
                acc = fmaf(r0.x, (V)[0], acc);                                  \
                acc = fmaf(r0.y, (V)[1], acc);                                  \
                if (p >= 1) { acc = fmaf(r0.z, (V)[2], acc);                    \
                              acc = fmaf(r0.w, (V)[3], acc); }                  \
                if (p >= 2) {                                                   \
                    float4 r1 = row[1];                                         \
                    acc = fmaf(r1.x, (V)[4], acc);                              \
                    acc = fmaf(r1.y, (V)[5], acc);                              \
                    if (p >= 3) { acc = fmaf(r1.z, (V)[6], acc);                \
                                  acc = fmaf(r1.w, (V)[7], acc); }              \
                }                                                               \
                if (p >= 4) {                                                   \
                    float4 r2 = row[2];                                         \
                    acc = fmaf(r2.x, (V)[8], acc);                              \
                    acc = fmaf(r2.y, (V)[9], acc);                              \
                    if (p >= 5) { acc = fmaf(r2.z, (V)[10], acc);               \
                                  acc = fmaf(r2.w, (V)[11], acc); }             \
                }                                                               \
                if (rq == 0) o0 = acc; else o1 = acc;                           \
            }                                                                   \
            (V)[2 * p] = o0; (V)[2 * p + 1] = o1;                               \
        }                                                                       \
    }

// ---------------------------------------------------------------------------
// k_seed: one 256-thread block per signal; thread t owns samples [t*64,+64).
// No stash, no staging -> low regs, high occupancy.
//   passA: zero-state filter (output discarded); capture s_half @ sample 32
//   scan : 5-round wave-local TRI shuffle scan (R9-verified)
//   seeds: si (sample t*64) and s_mid = A^32*si + s_half (sample t*64+32)
//          -> g_seed[sig][2t], g_seed[sig][2t+1]
// ---------------------------------------------------------------------------
__global__ void __launch_bounds__(256, 4)
k_seed(const float* __restrict__ x, const float* __restrict__ sos) {
    __shared__ float Mp[NTAB][NMAT];     // 3.46 KB
    __shared__ float cw[4][NSTATE];

    const int k = threadIdx.x;
    const int lane = k & 63;
    const int w = k >> 6;
    const int sig = blockIdx.x;

    for (int i = k; i < NTAB * NMAT; i += 256)
        Mp[i / NMAT][i % NMAT] = g_Mp[i];

    float b0[NSEC], b1[NSEC], b2[NSEC], a1[NSEC], a2[NSEC];
#pragma unroll
    for (int i = 0; i < NSEC; ++i) {
        b0[i] = rfl(sos[i * 6 + 0]);
        b1[i] = rfl(sos[i * 6 + 1]);
        b2[i] = rfl(sos[i * 6 + 2]);
        a1[i] = rfl(sos[i * 6 + 4]);
        a2[i] = rfl(sos[i * 6 + 5]);
    }

    float w1_[NSEC], w2_[NSEC];
    auto fstep = [&](float cur) -> float {
#pragma unroll
        for (int i = 0; i < NSEC; ++i) {
            float yv = fmaf(b0[i], cur, w1_[i]);
            w1_[i] = fmaf(b1[i], cur, fmaf(-a1[i], yv, w2_[i]));
            w2_[i] = fmaf(b2[i], cur, -(a2[i] * yv));
            cur = yv;
        }
        return cur;
    };

    // ---- pass A: zero-state filter; capture s_half after 32 samples ----
    const float4* xp4 = (const float4*)(x + (size_t)sig * T_LEN) + k * 16;
    float sh1[NSEC], sh2[NSEC];
#pragma unroll
    for (int i = 0; i < NSEC; ++i) { w1_[i] = 0.f; w2_[i] = 0.f; }
#pragma unroll
    for (int m = 0; m < 16; ++m) {
        float4 v = xp4[m];
        fstep(v.x); fstep(v.y); fstep(v.z); fstep(v.w);
        if (m == 7) {
#pragma unroll
            for (int i = 0; i < NSEC; ++i) { sh1[i] = w1_[i]; sh2[i] = w2_[i]; }
        }
    }
    float c0[NSTATE];
#pragma unroll
    for (int i = 0; i < NSEC; ++i) { c0[2 * i] = w1_[i]; c0[2 * i + 1] = w2_[i]; }

    __syncthreads();   // Mp staged

    // ---- wave-local inclusive scan: 5 TRI shuffle rounds (window 32) ----
#pragma unroll
    for (int rnd = 0; rnd < NPOW; ++rnd) {
        const int d = 1 << rnd;
        float pr[NSTATE];
#pragma unroll
        for (int j = 0; j < NSTATE; ++j) pr[j] = __shfl_up(c0[j], d, 64);
        if (lane >= d) {
            TRI_MATVEC_IP(Mp[rnd], pr, c0[2 * p], c0[2 * p + 1]);
#pragma unroll
            for (int j = 0; j < NSTATE; ++j) c0[j] = pr[j];
        }
    }

    if (lane == 63) {
#pragma unroll
        for (int j = 0; j < NSTATE; ++j) cw[w][j] = c0[j];
    }
    __syncthreads();

    // ---- seed si = exclusive scan; waves>0 lanes<32 add M^lane * T_prev ----
    float si[NSTATE];
#pragma unroll
    for (int j = 0; j < NSTATE; ++j) {
        si[j] = __shfl_up(c0[j], 1, 64);
        if (lane == 0) si[j] = 0.f;
    }
    if (w > 0 && lane < 32) {
        float u[NSTATE];
#pragma unroll
        for (int j = 0; j < NSTATE; ++j) u[j] = cw[w - 1][j];
#pragma unroll
        for (int i = 0; i < NPOW; ++i) {
            if ((lane >> i) & 1) {
                TRI_MATVEC_IP(Mp[i], u, 0.f, 0.f);
            }
        }
#pragma unroll
        for (int j = 0; j < NSTATE; ++j) si[j] += u[j];
    }

    // ---- s_mid = A^32 * si + s_half ----
    float sm[NSTATE];
#pragma unroll
    for (int j = 0; j < NSTATE; ++j) sm[j] = si[j];
    TRI_MATVEC_IP(Mp[5], sm, sh1[p], sh2[p]);

    // ---- emit both seeds (24 contiguous floats per thread) ----
    float* sp = g_seed + ((size_t)sig * 512 + 2 * k) * NSTATE;
#pragma unroll
    for (int j = 0; j < NSTATE; ++j) sp[j] = si[j];
#pragma unroll
    for (int j = 0; j < NSTATE; ++j) sp[NSTATE + j] = sm[j];
}

// ---------------------------------------------------------------------------
// k_apply: one 512-thread block per signal; thread u owns samples [u*32,+32).
// Reads seed, runs the exact seeded recurrence, stages via 2x32KB LDS swizzle
// (R11-verified clean writes), stores coalesced.
// ---------------------------------------------------------------------------
__global__ void __launch_bounds__(512, 6)
k_apply(const float* __restrict__ x, const float* __restrict__ sos,
        float* __restrict__ y) {
    __shared__ float4 sm4[2048];         // 32 KB write-stage

    const int k = threadIdx.x;
    const int sig = blockIdx.x;

    float b0[NSEC], b1[NSEC], b2[NSEC], a1[NSEC], a2[NSEC];
#pragma unroll
    for (int i = 0; i < NSEC; ++i) {
        b0[i] = rfl(sos[i * 6 + 0]);
        b1[i] = rfl(sos[i * 6 + 1]);
        b2[i] = rfl(sos[i * 6 + 2]);
        a1[i] = rfl(sos[i * 6 + 4]);
        a2[i] = rfl(sos[i * 6 + 5]);
    }

    // seed state
    const float* sp = g_seed + ((size_t)sig * 512 + k) * NSTATE;
    float w1_[NSEC], w2_[NSEC];
#pragma unroll
    for (int i = 0; i < NSEC; ++i) { w1_[i] = sp[2 * i]; w2_[i] = sp[2 * i + 1]; }

    auto fstep = [&](float cur) -> float {
#pragma unroll
        for (int i = 0; i < NSEC; ++i) {
            float yv = fmaf(b0[i], cur, w1_[i]);
            w1_[i] = fmaf(b1[i], cur, fmaf(-a1[i], yv, w2_[i]));
            w2_[i] = fmaf(b2[i], cur, -(a2[i] * yv));
            cur = yv;
        }
        return cur;
    };

    // ---- seeded filter over 32 samples (exact recurrence) ----
    const float4* xp4 = (const float4*)(x + (size_t)sig * T_LEN) + k * 8;
    float4 stash[8];
#pragma unroll
    for (int m = 0; m < 8; ++m) {
        float4 v = xp4[m];
        v.x = fstep(v.x); v.y = fstep(v.y); v.z = fstep(v.z); v.w = fstep(v.w);
        stash[m] = v;
    }

    // ---- write staging: 2 rounds x 32KB, 8-f4-row XOR swizzle (R11) ----
    float4* yp4 = (float4*)(y + (size_t)sig * T_LEN);
#pragma unroll 1
    for (int r = 0; r < 2; ++r) {
        __syncthreads();
        if ((k >> 8) == r) {
            const int t8 = k & 255;
#pragma unroll
            for (int m = 0; m < 8; ++m)
                sm4[t8 * 8 + (m ^ (t8 & 7))] = stash[m];
        }
        __syncthreads();
#pragma unroll
        for (int q = 0; q < 4; ++q) {
            int j = k + 512 * q;                      // 0..2047
            int s = (j & ~7) | ((j ^ (j >> 3)) & 7);  // matches writer swizzle
            yp4[r * 2048 + j] = sm4[s];
        }
    }
}

extern "C" void kernel_launch(void* const* d_in, const int* in_sizes, int n_in,
                              void* d_out, int out_size, void* d_ws, size_t ws_size,
                              hipStream_t stream) {
    const float* x   = (const float*)d_in[0];
    const float* sos = (const float*)d_in[1];
    if (n_in >= 2 && in_sizes[0] <= 256 && in_sizes[1] > 256) {  // insurance
        x = (const float*)d_in[1];
        sos = (const float*)d_in[0];
    }
    float* out = (float*)d_out;

    int NS = out_size / T_LEN;      // 2048 signals
    if (NS > NS_TOT) NS = NS_TOT;
    if (NS < 1) NS = 1;

    k_matpow<<<1, 256, 0, stream>>>(sos);
    k_seed<<<NS, 256, 0, stream>>>(x, sos);
    k_apply<<<NS, 512, 0, stream>>>(x, sos, out);
}

// Round 16
// 109.556 us; speedup vs baseline: 3.8381x; 1.1374x over previous
//
#include <hip/hip_runtime.h>

#define T_LEN 16384
#define NSEC 6                   // order-5 butter = 3 SOS each (hp+lp)
#define NSTATE 12
#define NMAT (NSTATE * NSTATE)   // 144
#define NTAB 6                   // [0]=A^32, [1..5]=(A^128)^(2^i), i=0..4
#define NS_TOT 2048

__device__ float g_Mp[NTAB * NMAT];

__device__ __forceinline__ float rfl(float v) {
    return __int_as_float(__builtin_amdgcn_readfirstlane(__float_as_int(v)));
}

// ---------------------------------------------------------------------------
// Build one-step transition A (fp64); square 11x. Store A^32 (it=5) -> slot 0,
// A^(2^it) for it=7..11 -> slots 1..5 ( = (A^128)^(2^i), i=0..4 ).
// ---------------------------------------------------------------------------
__global__ void k_matpow(const float* __restrict__ sos) {
    __shared__ double A[NMAT];
    int tid = threadIdx.x;

    if (tid < NSTATE) {
        double b0[NSEC], b1[NSEC], b2[NSEC], a1[NSEC], a2[NSEC];
#pragma unroll
        for (int i = 0; i < NSEC; ++i) {
            b0[i] = (double)sos[i * 6 + 0];
            b1[i] = (double)sos[i * 6 + 1];
            b2[i] = (double)sos[i * 6 + 2];
            a1[i] = (double)sos[i * 6 + 4];
            a2[i] = (double)sos[i * 6 + 5];
        }
        double w1[NSEC], w2[NSEC];
#pragma unroll
        for (int i = 0; i < NSEC; ++i) {
            w1[i] = (tid == 2 * i) ? 1.0 : 0.0;
            w2[i] = (tid == 2 * i + 1) ? 1.0 : 0.0;
        }
        double cur = 0.0;   // zero input: unit-state probe, one step
#pragma unroll
        for (int i = 0; i < NSEC; ++i) {
            double yv = fma(b0[i], cur, w1[i]);
            double n1 = fma(b1[i], cur, fma(-a1[i], yv, w2[i]));
            double n2 = fma(b2[i], cur, -(a2[i] * yv));
            w1[i] = n1; w2[i] = n2; cur = yv;
        }
#pragma unroll
        for (int i = 0; i < NSEC; ++i) {
            A[(2 * i) * NSTATE + tid]     = w1[i];   // column tid
            A[(2 * i + 1) * NSTATE + tid] = w2[i];
        }
    }
    __syncthreads();

    const int rr = tid / NSTATE, cc = tid % NSTATE;
    for (int it = 1; it <= 11; ++it) {
        double v = 0.0;
        if (tid < NMAT) {
#pragma unroll
            for (int kk = 0; kk < NSTATE; ++kk)
                v = fma(A[rr * NSTATE + kk], A[kk * NSTATE + cc], v);
        }
        __syncthreads();
        if (tid < NMAT) {
            A[rr * NSTATE + cc] = v;
            if (it == 5) g_Mp[0 * NMAT + tid] = (float)v;           // A^32
            if (it >= 7) g_Mp[(it - 6) * NMAT + tid] = (float)v;    // (A^128)^(2^i)
        }
        __syncthreads();
    }
}

// In-place block-triangular matvec: V <- M*V + EXTRA (expressions in p).
// M block-lower-triangular (biquad cascade): rows 2p,2p+1 read V[0..2p+1]
// only -> pair-descending in-place safe. Rows read as float4 (LDS broadcast).
#define TRI_MATVEC_IP(MBASE, V, EXTRA0, EXTRA1)                                 \
    {                                                                           \
        _Pragma("unroll")                                                       \
        for (int p = 5; p >= 0; --p) {                                          \
            float o0, o1;                                                       \
            _Pragma("unroll")                                                   \
            for (int rq = 0; rq < 2; ++rq) {                                    \
                const int q = 2 * p + rq;                                       \
                const float4* row = (const float4*)((MBASE) + q * NSTATE);      \
                float acc = (rq == 0 ? (EXTRA0) : (EXTRA1));                    \
                float4 r0 = row[0];                                             \
                acc = fmaf(r0.x, (V)[0], acc);                                  \
                acc = fmaf(r0.y, (V)[1], acc);                                  \
                if (p >= 1) { acc = fmaf(r0.z, (V)[2], acc);                    \
                              acc = fmaf(r0.w, (V)[3], acc); }                  \
                if (p >= 2) {                                                   \
                    float4 r1 = row[1];                                         \
                    acc = fmaf(r1.x, (V)[4], acc);                              \
                    acc = fmaf(r1.y, (V)[5], acc);                              \
                    if (p >= 3) { acc = fmaf(r1.z, (V)[6], acc);                \
                                  acc = fmaf(r1.w, (V)[7], acc); }              \
                }                                                               \
                if (p >= 4) {                                                   \
                    float4 r2 = row[2];                                         \
                    acc = fmaf(r2.x, (V)[8], acc);                              \
                    acc = fmaf(r2.y, (V)[9], acc);                              \
                    if (p >= 5) { acc = fmaf(r2.z, (V)[10], acc);               \
                                  acc = fmaf(r2.w, (V)[11], acc); }             \
                }                                                               \
                if (rq == 0) o0 = acc; else o1 = acc;                           \
            }                                                                   \
            (V)[2 * p] = o0; (V)[2 * p + 1] = o1;                               \
        }                                                                       \
    }

// ---------------------------------------------------------------------------
// One 128-thread block per signal. Thread t owns samples [t*128, +128) as
// 4 independent 32-sample chains (ILP-4 in pass A).
//   passA: 4 zero-state chains interleaved -> end states b_0..b_3 (outputs dropped)
//   fold : T = b3 + A32*(b2 + A32*(b1 + A32*b0))   (3 TRI matvecs)
//   scan : 5-round wave scan with M=A^128 (window 32, decay-safe)
//   seed : si = excl scan; wave1 lanes<32 add M^lane * T_wave0 (R9-verified)
//   passB: 4 rounds; round r refilters chain r seeded by the RUNNING state
//          (end state of round r IS round r+1's seed), stages 8 f4 in LDS
//          (XOR swizzle), consumers store 8 full 128B lines per instruction.
// ---------------------------------------------------------------------------
__global__ void __launch_bounds__(128, 4)
k_main(const float* __restrict__ x, const float* __restrict__ sos,
       float* __restrict__ y) {
    __shared__ float Mp[NTAB][NMAT];     // 3.46 KB
    __shared__ float cw[2][NSTATE];
    __shared__ float4 sm4[1024];         // 16 KB stage buffer

    const int k = threadIdx.x;           // 0..127
    const int lane = k & 63;
    const int w = k >> 6;                // wave 0..1
    const int sig = blockIdx.x;

    for (int i = k; i < NTAB * NMAT; i += 128)
        Mp[i / NMAT][i % NMAT] = g_Mp[i];

    // coefficients -> SGPRs
    float b0[NSEC], b1[NSEC], b2[NSEC], a1[NSEC], a2[NSEC];
#pragma unroll
    for (int i = 0; i < NSEC; ++i) {
        b0[i] = rfl(sos[i * 6 + 0]);
        b1[i] = rfl(sos[i * 6 + 1]);
        b2[i] = rfl(sos[i * 6 + 2]);
        a1[i] = rfl(sos[i * 6 + 4]);
        a2[i] = rfl(sos[i * 6 + 5]);
    }

    const float4* xb = (const float4*)(x + (size_t)sig * T_LEN) + k * 32;

    // ---- pass A: 4 interleaved zero-state chains (ILP-4) ----
    float W1[4][NSEC], W2[4][NSEC];
#pragma unroll
    for (int j = 0; j < 4; ++j)
#pragma unroll
        for (int i = 0; i < NSEC; ++i) { W1[j][i] = 0.f; W2[j][i] = 0.f; }

    auto stepc = [&](int j, float cur) {
#pragma unroll
        for (int i = 0; i < NSEC; ++i) {
            float yv = fmaf(b0[i], cur, W1[j][i]);
            W1[j][i] = fmaf(b1[i], cur, fmaf(-a1[i], yv, W2[j][i]));
            W2[j][i] = fmaf(b2[i], cur, -(a2[i] * yv));
            cur = yv;
        }
    };

#pragma unroll
    for (int m = 0; m < 8; ++m) {
        float4 v0 = xb[0 * 8 + m], v1 = xb[1 * 8 + m];
        float4 v2 = xb[2 * 8 + m], v3 = xb[3 * 8 + m];
        stepc(0, v0.x); stepc(1, v1.x); stepc(2, v2.x); stepc(3, v3.x);
        stepc(0, v0.y); stepc(1, v1.y); stepc(2, v2.y); stepc(3, v3.y);
        stepc(0, v0.z); stepc(1, v1.z); stepc(2, v2.z); stepc(3, v3.z);
        stepc(0, v0.w); stepc(1, v1.w); stepc(2, v2.w); stepc(3, v3.w);
    }

    __syncthreads();   // Mp staged (fold below uses Mp[0])

    // ---- fold: T = state after 128 samples from zero ----
    float T[NSTATE];
#pragma unroll
    for (int i = 0; i < NSEC; ++i) { T[2 * i] = W1[0][i]; T[2 * i + 1] = W2[0][i]; }
#pragma unroll
    for (int j = 1; j < 4; ++j) {
        TRI_MATVEC_IP(Mp[0], T, W1[j][p], W2[j][p]);
    }

    // ---- wave-local inclusive scan: 5 rounds, M = A^128 ----
    float c0[NSTATE];
#pragma unroll
    for (int j = 0; j < NSTATE; ++j) c0[j] = T[j];
#pragma unroll
    for (int rnd = 0; rnd < 5; ++rnd) {
        const int d = 1 << rnd;
        float pr[NSTATE];
#pragma unroll
        for (int j = 0; j < NSTATE; ++j) pr[j] = __shfl_up(c0[j], d, 64);
        if (lane >= d) {
            TRI_MATVEC_IP(Mp[1 + rnd], pr, c0[2 * p], c0[2 * p + 1]);
#pragma unroll
            for (int j = 0; j < NSTATE; ++j) c0[j] = pr[j];
        }
    }

    if (lane == 63) {
#pragma unroll
        for (int j = 0; j < NSTATE; ++j) cw[w][j] = c0[j];
    }
    __syncthreads();

    // ---- seed: si = exclusive scan; wave1 lanes<32 add M^lane * T_wave0 ----
    float si[NSTATE];
#pragma unroll
    for (int j = 0; j < NSTATE; ++j) {
        si[j] = __shfl_up(c0[j], 1, 64);
        if (lane == 0) si[j] = 0.f;
    }
    if (w > 0 && lane < 32) {
        float u[NSTATE];
#pragma unroll
        for (int j = 0; j < NSTATE; ++j) u[j] = cw[0][j];
#pragma unroll
        for (int i = 0; i < 5; ++i) {
            if ((lane >> i) & 1) {
                TRI_MATVEC_IP(Mp[1 + i], u, 0.f, 0.f);
            }
        }
#pragma unroll
        for (int j = 0; j < NSTATE; ++j) si[j] += u[j];
    }

    // ---- pass B: 4 rounds; running state propagates chain-to-chain ----
    float w1_[NSEC], w2_[NSEC];
#pragma unroll
    for (int i = 0; i < NSEC; ++i) { w1_[i] = si[2 * i]; w2_[i] = si[2 * i + 1]; }

    auto fstep = [&](float cur) -> float {
#pragma unroll
        for (int i = 0; i < NSEC; ++i) {
            float yv = fmaf(b0[i], cur, w1_[i]);
            w1_[i] = fmaf(b1[i], cur, fmaf(-a1[i], yv, w2_[i]));
            w2_[i] = fmaf(b2[i], cur, -(a2[i] * yv));
            cur = yv;
        }
        return cur;
    };

    float4* yb = (float4*)(y + (size_t)sig * T_LEN);
    for (int r = 0; r < 4; ++r) {
        // producer: refilter chain r (x re-read: L2/L3), stage swizzled
#pragma unroll
        for (int m = 0; m < 8; ++m) {
            float4 v = xb[r * 8 + m];
            v.x = fstep(v.x); v.y = fstep(v.y); v.z = fstep(v.z); v.w = fstep(v.w);
            sm4[k * 8 + (m ^ (k & 7))] = v;
        }
        __syncthreads();
        // consumer: each instruction writes 8 FULL 128B lines (8 lanes/line)
#pragma unroll
        for (int q = 0; q < 8; ++q) {
            int R = q * 128 + k;                // 0..1023
            int tt = R >> 3;
            int mm = R & 7;
            yb[tt * 32 + r * 8 + mm] = sm4[tt * 8 + (mm ^ (tt & 7))];
        }
        __syncthreads();
    }
}

extern "C" void kernel_launch(void* const* d_in, const int* in_sizes, int n_in,
                              void* d_out, int out_size, void* d_ws, size_t ws_size,
                              hipStream_t stream) {
    const float* x   = (const float*)d_in[0];
    const float* sos = (const float*)d_in[1];
    if (n_in >= 2 && in_sizes[0] <= 256 && in_sizes[1] > 256) {  // insurance
        x = (const float*)d_in[1];
        sos = (const float*)d_in[0];
    }
    float* out = (float*)d_out;

    int NS = out_size / T_LEN;      // 2048 signals
    if (NS > NS_TOT) NS = NS_TOT;
    if (NS < 1) NS = 1;

    k_matpow<<<1, 256, 0, stream>>>(sos);
    k_main<<<NS, 128, 0, stream>>>(x, sos, out);
}